// Round 1
// 453.790 us; speedup vs baseline: 1.0280x; 1.0280x over previous
//
#include <hip/hip_runtime.h>

// BlockResMLP MixerBlock: 2 layers of 64 independent block MLPs (64->128->64, ELU, residual)
// with a per-row 64x64 transpose (shuffle) around layer 2.
// bf16 MFMA (16x16x32), fp32 accumulate. 3 kernels:
//   k0: weight convert+transpose (LDS transpose, coalesced)
//   k1: layer-1 facto, writes y1 in granule-16 layout [row>>4][i][m][row&15] (512B-run stores)
//   k2: layer-2 facto + inverse shuffle + fp32 out, fused. WG = 16 rows x 16 m-blocks.
//       y1 tile -> LDS transpose -> MFMA -> in-place y2 writeback in LDS -> coalesced out.

typedef short short8 __attribute__((ext_vector_type(8)));
typedef float floatx4 __attribute__((ext_vector_type(4)));

#define MFMA(A, B, C) __builtin_amdgcn_mfma_f32_16x16x32_bf16((A), (B), (C), 0, 0, 0)

__device__ __forceinline__ unsigned short bf16r(float f) {
  unsigned int u = __builtin_bit_cast(unsigned int, f);
  u += 0x7FFFu + ((u >> 16) & 1u);   // round-to-nearest-even
  return (unsigned short)(u >> 16);
}
__device__ __forceinline__ float bf16f(unsigned short h) {
  unsigned int u = ((unsigned int)h) << 16;
  return __builtin_bit_cast(float, u);
}
__device__ __forceinline__ float eluf(float v) {
  return v > 0.f ? v : (__expf(v) - 1.f);
}
__device__ __forceinline__ uint4 gather8(const short* base, int stride) {
  uint4 o;
  o.x = (unsigned int)(unsigned short)base[0 * stride] |
        ((unsigned int)(unsigned short)base[1 * stride] << 16);
  o.y = (unsigned int)(unsigned short)base[2 * stride] |
        ((unsigned int)(unsigned short)base[3 * stride] << 16);
  o.z = (unsigned int)(unsigned short)base[4 * stride] |
        ((unsigned int)(unsigned short)base[5 * stride] << 16);
  o.w = (unsigned int)(unsigned short)base[6 * stride] |
        ((unsigned int)(unsigned short)base[7 * stride] << 16);
  return o;
}

// ---------------- K0: weight prep (LDS transpose) ----------------
// w1 fp32 [l][n][d][e] (2,64,64,128)  -> w1t bf16 [l*64+n][e][d]
// w2 fp32 [l][n][e][d'] (2,64,128,64) -> w2t bf16 [l*64+n][d'][e]
// grid 256: blockIdx = ln*2 + phase
__global__ __launch_bounds__(256) void k0_prep(const float* __restrict__ w1,
                                               const float* __restrict__ w2,
                                               short* __restrict__ w1t,
                                               short* __restrict__ w2t) {
  __shared__ __align__(16) short T[128 * 72];   // phase A uses [64][136] = 8704 shorts
  const int t  = threadIdx.x;
  const int ln = blockIdx.x >> 1;
  if ((blockIdx.x & 1) == 0) {
    // ---- w1 [64 d][128 e] -> w1t [e][d] ----
    const float* src = w1 + (size_t)ln * 8192 + t * 32;
    const int d = t >> 2, e0 = (t & 3) * 32;
#pragma unroll
    for (int u = 0; u < 32; u += 2) {
      float f0 = src[u], f1 = src[u + 1];
      unsigned int pk = (unsigned int)bf16r(f0) | ((unsigned int)bf16r(f1) << 16);
      *(unsigned int*)&T[d * 136 + e0 + u] = pk;
    }
    __syncthreads();
    const int e = t >> 1, d0 = (t & 1) * 32;
    short* dst = w1t + (size_t)ln * 8192 + e * 64 + d0;
#pragma unroll
    for (int k = 0; k < 4; ++k)
      *(uint4*)(dst + k * 8) = gather8(&T[(d0 + k * 8) * 136 + e], 136);
  } else {
    // ---- w2 [128 e][64 d'] -> w2t [d'][e] ----
    const float* src = w2 + (size_t)ln * 8192 + t * 32;
    const int e = t >> 1, d0 = (t & 1) * 32;
#pragma unroll
    for (int u = 0; u < 32; u += 2) {
      float f0 = src[u], f1 = src[u + 1];
      unsigned int pk = (unsigned int)bf16r(f0) | ((unsigned int)bf16r(f1) << 16);
      *(unsigned int*)&T[e * 72 + d0 + u] = pk;
    }
    __syncthreads();
    const int dp = t >> 2, e0 = (t & 3) * 32;
    short* dst = w2t + (size_t)ln * 8192 + dp * 128 + e0;
#pragma unroll
    for (int k = 0; k < 4; ++k)
      *(uint4*)(dst + k * 8) = gather8(&T[(e0 + k * 8) * 72 + dp], 72);
  }
}

// ---------------- K1: layer 0 facto ----------------
// WG = (n-pair x 64 rows), 4 waves. A-frags hoisted.
// y1 layout: [row>>4][n][j][row&15] bf16 -> stores are fully contiguous 512B runs.
__global__ __launch_bounds__(256) void k1_layer0(
    const float* __restrict__ x,
    const short* __restrict__ w1t, const short* __restrict__ w2t,
    const float* __restrict__ b1,  const float* __restrict__ b2,
    short* __restrict__ y1) {
  __shared__ __align__(16) short hst[4][2][16][72];
  const int tid  = threadIdx.x;
  const int lane = tid & 63;
  const int wv   = tid >> 6;
  const int il   = lane & 15;
  const int q    = lane >> 4;
  const int npair   = blockIdx.x & 31;
  const int rowtile = blockIdx.x >> 5;
  const int n  = npair * 2 + (wv & 1);
  const int r0 = rowtile * 64 + (wv >> 1) * 32;     // 32-row aligned

  const short* w1n = w1t + (size_t)n * 8192;
  const short* w2n = w2t + (size_t)n * 8192;
  const float* b1n = b1 + n * 128;
  const float* b2n = b2 + n * 64;

  // hoisted A-frags: load + convert x once
  short8 a[2][2];   // [ks][Mt]
#pragma unroll
  for (int Mt = 0; Mt < 2; ++Mt) {
#pragma unroll
    for (int ks = 0; ks < 2; ++ks) {
      const float* xp = x + (size_t)(r0 + Mt * 16 + il) * 4096 + n * 64 + ks * 32 + q * 8;
      floatx4 f0 = *(const floatx4*)xp;
      floatx4 f1 = *(const floatx4*)(xp + 4);
      short8 t;
#pragma unroll
      for (int u = 0; u < 4; ++u) { t[u] = (short)bf16r(f0[u]); t[4 + u] = (short)bf16r(f1[u]); }
      a[ks][Mt] = t;
    }
  }

  floatx4 acc2[2][4] = {};
  for (int hh = 0; hh < 2; ++hh) {
    floatx4 acc1[2][4] = {};
#pragma unroll
    for (int ks = 0; ks < 2; ++ks) {
#pragma unroll
      for (int nt = 0; nt < 4; ++nt) {
        short8 b = *(const short8*)(w1n + (hh * 64 + nt * 16 + il) * 64 + ks * 32 + q * 8);
        acc1[0][nt] = MFMA(a[ks][0], b, acc1[0][nt]);
        acc1[1][nt] = MFMA(a[ks][1], b, acc1[1][nt]);
      }
    }
    // epilogue 1: bias + ELU -> h stage (bf16)
#pragma unroll
    for (int nt = 0; nt < 4; ++nt) {
      float bias = b1n[hh * 64 + nt * 16 + il];
#pragma unroll
      for (int Mt = 0; Mt < 2; ++Mt)
#pragma unroll
        for (int rg = 0; rg < 4; ++rg) {
          float v = acc1[Mt][nt][rg] + bias;
          hst[wv][Mt][q * 4 + rg][nt * 16 + il] = (short)bf16r(eluf(v));
        }
    }
    asm volatile("s_waitcnt lgkmcnt(0)" ::: "memory");
#pragma unroll
    for (int ks2 = 0; ks2 < 2; ++ks2) {
      short8 a2[2];
      a2[0] = *(const short8*)&hst[wv][0][il][ks2 * 32 + q * 8];
      a2[1] = *(const short8*)&hst[wv][1][il][ks2 * 32 + q * 8];
#pragma unroll
      for (int nt2 = 0; nt2 < 4; ++nt2) {
        short8 b = *(const short8*)(w2n + (nt2 * 16 + il) * 128 + hh * 64 + ks2 * 32 + q * 8);
        acc2[0][nt2] = MFMA(a2[0], b, acc2[0][nt2]);
        acc2[1][nt2] = MFMA(a2[1], b, acc2[1][nt2]);
      }
    }
    asm volatile("s_waitcnt lgkmcnt(0)" ::: "memory");
  }
  // epilogue 2: bias + fp32 residual from x (L1/L2-hot),
  // store to y1[(row>>4)][n][j][row&15] -- contiguous 512B runs per (Mt,instr)
#pragma unroll
  for (int Mt = 0; Mt < 2; ++Mt) {
    const int R0 = r0 + Mt * 16 + q * 4;
    const size_t nbase = ((size_t)((r0 + Mt * 16) >> 4) * 64 + n) * 64;
#pragma unroll
    for (int nt2 = 0; nt2 < 4; ++nt2) {
      const int j = nt2 * 16 + il;
      const float bias = b2n[j];
      float v0 = acc2[Mt][nt2][0] + bias + x[(size_t)(R0 + 0) * 4096 + n * 64 + j];
      float v1 = acc2[Mt][nt2][1] + bias + x[(size_t)(R0 + 1) * 4096 + n * 64 + j];
      float v2 = acc2[Mt][nt2][2] + bias + x[(size_t)(R0 + 2) * 4096 + n * 64 + j];
      float v3 = acc2[Mt][nt2][3] + bias + x[(size_t)(R0 + 3) * 4096 + n * 64 + j];
      uint2 pk;
      pk.x = (unsigned int)bf16r(v0) | ((unsigned int)bf16r(v1) << 16);
      pk.y = (unsigned int)bf16r(v2) | ((unsigned int)bf16r(v3) << 16);
      *(uint2*)(y1 + (nbase + j) * 16 + q * 4) = pk;
    }
  }
}

// ---------------- K2: layer 1 facto + inverse shuffle + fp32 out (fused) ----------------
// WG = 16 rows (one rt16) x 16 m-blocks, 4 waves; wave owns 4 m's.
// zL2[m][r][i]: m-stride 1160 shorts (16*72+8), r-stride 72. Loaded coalesced (512B runs),
// transposed via register scatter. Epilogue writes y2 bf16 IN PLACE over z2 (same-lane RMW).
// Final pass: gather 16 m's per (r,i), write out[row][i*64+m] in 64B sectors.
__global__ __launch_bounds__(256) void k2_layer1_out(
    const short* __restrict__ y1,
    const short* __restrict__ w1t, const short* __restrict__ w2t,
    const float* __restrict__ b1,  const float* __restrict__ b2,
    float* __restrict__ out) {
  __shared__ __align__(16) short zL2[16 * 1160];
  __shared__ __align__(16) short hs[4][16][72];
  const int tid  = threadIdx.x;
  const int lane = tid & 63;
  const int wv   = tid >> 6;
  const int il   = lane & 15;
  const int q    = lane >> 4;
  const int rt16 = blockIdx.x & 511;        // row tile (16 rows)
  const int m0   = (blockIdx.x >> 9) * 16;  // m window

  // ---- load z2 tile (32KB, coalesced) + transpose into zL2[m][r][i] ----
  {
    const int i   = tid >> 2;
    const int sub = tid & 3;
    const short* src = y1 + ((size_t)(rt16 * 64 + i) * 64 + m0 + sub * 4) * 16;
#pragma unroll
    for (int j = 0; j < 8; ++j) {
      uint4 w = *(const uint4*)(src + j * 8);
      const int mm = j >> 1;
      const int rb = (j & 1) * 8;
      unsigned int c[4] = {w.x, w.y, w.z, w.w};
      short* zb = zL2 + (sub * 4 + mm) * 1160 + i;
#pragma unroll
      for (int h = 0; h < 4; ++h) {
        zb[(rb + h * 2 + 0) * 72] = (short)(c[h] & 0xffffu);
        zb[(rb + h * 2 + 1) * 72] = (short)(c[h] >> 16);
      }
    }
  }
  __syncthreads();

#pragma unroll
  for (int mi = 0; mi < 4; ++mi) {
    const int ml = wv * 4 + mi;
    const int m  = m0 + ml;
    const short* w1m = w1t + (size_t)(64 + m) * 8192;
    const short* w2m = w2t + (size_t)(64 + m) * 8192;
    const float* b1m = b1 + (64 + m) * 128;
    const float* b2m = b2 + (64 + m) * 64;
    short* zrow = zL2 + ml * 1160;   // [r*72 + i]

    floatx4 acc2[4] = {};
    for (int hh = 0; hh < 2; ++hh) {
      floatx4 acc1[4] = {};
#pragma unroll
      for (int ks = 0; ks < 2; ++ks) {
        short8 a = *(const short8*)(zrow + il * 72 + ks * 32 + q * 8);
#pragma unroll
        for (int nt = 0; nt < 4; ++nt) {
          short8 b = *(const short8*)(w1m + (hh * 64 + nt * 16 + il) * 64 + ks * 32 + q * 8);
          acc1[nt] = MFMA(a, b, acc1[nt]);
        }
      }
#pragma unroll
      for (int nt = 0; nt < 4; ++nt) {
        float bias = b1m[hh * 64 + nt * 16 + il];
#pragma unroll
        for (int rg = 0; rg < 4; ++rg)
          hs[wv][q * 4 + rg][nt * 16 + il] = (short)bf16r(eluf(acc1[nt][rg] + bias));
      }
      asm volatile("s_waitcnt lgkmcnt(0)" ::: "memory");
#pragma unroll
      for (int ks2 = 0; ks2 < 2; ++ks2) {
        short8 a2 = *(const short8*)&hs[wv][il][ks2 * 32 + q * 8];
#pragma unroll
        for (int nt2 = 0; nt2 < 4; ++nt2) {
          short8 b = *(const short8*)(w2m + (nt2 * 16 + il) * 128 + hh * 64 + ks2 * 32 + q * 8);
          acc2[nt2] = MFMA(a2, b, acc2[nt2]);
        }
      }
      asm volatile("s_waitcnt lgkmcnt(0)" ::: "memory");
    }
    // epilogue: bias + residual; write y2 bf16 IN PLACE over z2 (same lane reads+writes slot)
#pragma unroll
    for (int nt2 = 0; nt2 < 4; ++nt2) {
      const int i = nt2 * 16 + il;
      const float bias = b2m[i];
#pragma unroll
      for (int k = 0; k < 4; ++k) {
        short* slot = zrow + (q * 4 + k) * 72 + i;
        float r = bf16f((unsigned short)*slot);
        *slot = (short)bf16r(acc2[nt2][k] + bias + r);
      }
    }
  }
  __syncthreads();

  // ---- final: inverse shuffle, fp32 out. out[row][i*64 + m0+ml] = y2[row][ml][i] ----
  const int r = tid >> 4;
  const int c = tid & 15;
  float* orow = out + (size_t)(rt16 * 16 + r) * 4096 + m0;
#pragma unroll
  for (int k = 0; k < 4; ++k) {
    const int i = c * 4 + k;
    float vv[16];
#pragma unroll
    for (int ml = 0; ml < 16; ++ml)
      vv[ml] = bf16f((unsigned short)zL2[ml * 1160 + r * 72 + i]);
    float* op = orow + i * 64;
    floatx4 a0 = {vv[0],  vv[1],  vv[2],  vv[3]};
    floatx4 a1 = {vv[4],  vv[5],  vv[6],  vv[7]};
    floatx4 a2 = {vv[8],  vv[9],  vv[10], vv[11]};
    floatx4 a3 = {vv[12], vv[13], vv[14], vv[15]};
    *(floatx4*)(op + 0)  = a0;
    *(floatx4*)(op + 4)  = a1;
    *(floatx4*)(op + 8)  = a2;
    *(floatx4*)(op + 12) = a3;
  }
}

extern "C" void kernel_launch(void* const* d_in, const int* in_sizes, int n_in,
                              void* d_out, int out_size, void* d_ws, size_t ws_size,
                              hipStream_t stream) {
  const float* x  = (const float*)d_in[0];
  const float* w1 = (const float*)d_in[1];
  const float* b1 = (const float*)d_in[2];
  const float* w2 = (const float*)d_in[3];
  const float* b2 = (const float*)d_in[4];
  float* out = (float*)d_out;

  short* w1t = (short*)d_ws;
  short* w2t = w1t + (1u << 20);
  short* y1  = w2t + (1u << 20);

  hipLaunchKernelGGL(k0_prep,       dim3(256),  dim3(256), 0, stream, w1, w2, w1t, w2t);
  hipLaunchKernelGGL(k1_layer0,     dim3(4096), dim3(256), 0, stream, x, w1t, w2t, b1, b2, y1);
  hipLaunchKernelGGL(k2_layer1_out, dim3(2048), dim3(256), 0, stream, y1, w1t, w2t, b1, b2, out);
}